// Round 10
// baseline (99.028 us; speedup 1.0000x reference)
//
#include <hip/hip_runtime.h>

#define IMG_W 1024
#define IMG_H 1024

// Packed 2 x f16: one VGPR = one window position for two adjacent output px.
typedef _Float16 h2 __attribute__((ext_vector_type(2)));

__device__ __forceinline__ h2 mn(h2 a, h2 b) { return __builtin_elementwise_min(a, b); }
__device__ __forceinline__ h2 mx(h2 a, h2 b) { return __builtin_elementwise_max(a, b); }
__device__ __forceinline__ void ce(h2 &a, h2 &b) { h2 t = mn(a, b); b = mx(a, b); a = t; }
__device__ __forceinline__ h2 med3p(h2 a, h2 b, h2 c) {
    return mx(mn(a, b), mn(mx(a, b), c));
}
__device__ __forceinline__ h2 pkrtz(float a, float b) {
    return __builtin_bit_cast(h2, __builtin_amdgcn_cvt_pkrtz(a, b));
}
// 9-CE optimal sort5 (validated rounds 1-9)
__device__ __forceinline__ void sort5(h2 &a0, h2 &a1, h2 &a2, h2 &a3, h2 &a4) {
    ce(a0, a1); ce(a3, a4); ce(a2, a4); ce(a2, a3);
    ce(a0, a3); ce(a0, a2); ce(a1, a4); ce(a1, a3); ce(a1, a2);
}
// 5-CE sort4
__device__ __forceinline__ void sort4(h2 &a, h2 &b, h2 &c, h2 &d) {
    ce(a, b); ce(c, d); ce(a, c); ce(b, d); ce(b, c);
}

struct Row { h2 a, b, c, d, e; };      // sorted 5-wide window (packed 2 px)

__device__ __forceinline__ Row make_row(float w0, float w1, float w2,
                                        float w3, float w4, float w5) {
    h2 p0 = pkrtz(w0, w1), p1 = pkrtz(w1, w2), p2 = pkrtz(w2, w3),
       p3 = pkrtz(w3, w4), p4 = pkrtz(w4, w5);
    sort5(p0, p1, p2, p3, p4);
    return {p0, p1, p2, p3, p4};
}

// Interior: window cols gcx-2..gcx+3 all in-image; 3 x 8B-aligned float2 loads.
__device__ __forceinline__ Row load_row_i(const float* __restrict__ rowp, int gcx) {
    float2 f01 = *reinterpret_cast<const float2*>(rowp + gcx - 2);
    float2 f23 = *reinterpret_cast<const float2*>(rowp + gcx);
    float2 f45 = *reinterpret_cast<const float2*>(rowp + gcx + 2);
    return make_row(f01.x, f01.y, f23.x, f23.y, f45.x, f45.y);
}

// Edge blocks (bx 0/7): clamped scalar loads, zero out-of-image cols.
__device__ __forceinline__ Row load_row_e(const float* __restrict__ rowp, int gcx) {
    float w[6];
    #pragma unroll
    for (int j = 0; j < 6; ++j) {
        int c = gcx - 2 + j;
        int cc = min(max(c, 0), IMG_W - 1);
        float v = rowp[cc];
        w[j] = ((unsigned)c < (unsigned)IMG_W) ? v : 0.0f;
    }
    return make_row(w[0], w[1], w[2], w[3], w[4], w[5]);
}

// Forgetful selection: median (rank 6) of the 13 candidates (validated rounds 1-9).
__device__ __forceinline__ h2 tail13(h2 A, h2 B, h2 c1a, h2 c1b, h2 c1c,
                                     h2 c2a, h2 c2b, h2 c2c,
                                     h2 c3a, h2 c3b, h2 c3c, h2 D, h2 E) {
    ce(A, D); ce(c1a, c3a); ce(A, c1a);        // A = min8 (drop)
    ce(B, E); ce(c1b, c3b); ce(E, c3b);        // c3b = max8 (drop)
    h2 e0 = B, e1 = D, e2 = E, e3 = c1a, e4 = c1b, e5 = c3a, e6 = c1c;
    ce(e0, e1); ce(e2, e3); ce(e4, e5);
    ce(e0, e2); ce(e4, e6); ce(e0, e4);        // e0 = min7 (drop)
    ce(e1, e3); ce(e5, e6); ce(e3, e6);        // e6 = max7 (drop)
    h2 f0 = e1, f1 = e2, f2 = e3, f3 = e4, f4 = e5, f5 = c2a;
    ce(f0, f1); ce(f2, f3); ce(f4, f5);
    ce(f0, f2); ce(f0, f4);                    // f0 = min6 (drop)
    ce(f1, f3); ce(f3, f5);                    // f5 = max6 (drop)
    h2 g0 = f1, g1 = f2, g2 = f3, g3 = f4, g4 = c2b;
    ce(g0, g1); ce(g2, g3);
    ce(g0, g2); ce(g0, g4);                    // g0 = min5 (drop)
    ce(g1, g3); ce(g3, g4);                    // g4 = max5 (drop)
    h2 h0 = g1, h1 = g2, h2_ = g3, h3 = c2c;
    ce(h0, h1); ce(h2_, h3); ce(h0, h2_); ce(h1, h3);
    return med3p(h1, h2_, c3c);
}

// Two vertically adjacent windows sharing rows rb..re (validated rounds 4-9).
__device__ __forceinline__ void pair_medians(const Row &rb, const Row &rc, const Row &rd,
                                             const Row &re, const Row &ra, const Row &rf,
                                             h2 &out_lo, h2 &out_hi) {
    h2 s0, s1, s2, s3;
    s0 = rb.a; s1 = rc.a; s2 = rd.a; s3 = re.a; sort4(s0, s1, s2, s3);
    h2 Bl = mx(s3, ra.a), Al = mx(s2, mn(s3, ra.a));
    h2 Bh = mx(s3, rf.a), Ah = mx(s2, mn(s3, rf.a));
    s0 = rb.b; s1 = rc.b; s2 = rd.b; s3 = re.b; sort4(s0, s1, s2, s3);
    h2 c1al = s2, c1bl = s3, c1cl = mx(s1, ra.b);
    h2 c1ah = s2, c1bh = s3, c1ch = mx(s1, rf.b);
    s0 = rb.c; s1 = rc.c; s2 = rd.c; s3 = re.c; sort4(s0, s1, s2, s3);
    h2 c2al = s1, c2bl = s2, c2cl = med3p(s0, ra.c, s3);
    h2 c2ah = s1, c2bh = s2, c2ch = med3p(s0, rf.c, s3);
    s0 = rb.d; s1 = rc.d; s2 = rd.d; s3 = re.d; sort4(s0, s1, s2, s3);
    h2 c3al = s0, c3bl = s1, c3cl = mn(s2, ra.d);
    h2 c3ah = s0, c3bh = s1, c3ch = mn(s2, rf.d);
    s0 = rb.e; s1 = rc.e; s2 = rd.e; s3 = re.e; sort4(s0, s1, s2, s3);
    h2 Dl = mn(s0, ra.e), El = mn(s1, mx(s0, ra.e));
    h2 Dh = mn(s0, rf.e), Eh = mn(s1, mx(s0, rf.e));

    out_lo = tail13(Al, Bl, c1al, c1bl, c1cl, c2al, c2bl, c2cl, c3al, c3bl, c3cl, Dl, El);
    out_hi = tail13(Ah, Bh, c1ah, c1bh, c1ch, c2ah, c2bh, c2ch, c3ah, c3bh, c3ch, Dh, Eh);
}

// NO LDS, NO BARRIERS: block 64x4; lane = 2 adjacent cols x 8 rows (16 px).
// Each wave spans one ty => vertical-OOB branches are wave-uniform.
__global__ __launch_bounds__(256, 4) void median5x5_kernel(const float* __restrict__ x,
                                                           float* __restrict__ out) {
    const int tx = threadIdx.x;            // 0..63
    const int ty = threadIdx.y;            // 0..3
    const int bx = blockIdx.x;             // 0..7  (128 output cols each)
    const int by = blockIdx.y;             // 0..31 (32 output rows each)
    const int plane = blockIdx.z;
    const float* src = x + (size_t)plane * IMG_H * IMG_W;

    const int gcx = bx * 128 + 2 * tx;     // lane's first output col
    const int row0 = by * 32 + ty * 8;     // lane's first output row
    const bool eblk = (bx == 0) | (bx == 7);

    const h2 z = {(_Float16)0, (_Float16)0};
    const Row ZR = {z, z, z, z, z};

    // Row loader: zero-pad rows outside the image (wave-uniform branch),
    // edge blocks take the clamped-scalar path (block-uniform branch).
#define LROW(gy_) ( ((unsigned)(gy_) >= (unsigned)IMG_H) ? ZR                  \
                    : (eblk ? load_row_e(src + (size_t)(gy_) * IMG_W, gcx)     \
                            : load_row_i(src + (size_t)(gy_) * IMG_W, gcx)) )

    // Rolling 6-row register window over absolute rows row0-2 .. row0+9.
    Row S0 = LROW(row0 - 2), S1 = LROW(row0 - 1), S2 = LROW(row0 + 0),
        S3 = LROW(row0 + 1), S4 = LROW(row0 + 2), S5 = LROW(row0 + 3);

    float* dst = out + (size_t)plane * IMG_H * IMG_W + (size_t)row0 * IMG_W + gcx;
    h2 mlo, mhi;

#define EMIT(vv, m) do {                                                       \
        float2 o; o.x = (float)(m).x; o.y = (float)(m).y;                      \
        *reinterpret_cast<float2*>(dst + (size_t)(vv) * IMG_W) = o;            \
    } while (0)

    pair_medians(S1, S2, S3, S4, S0, S5, mlo, mhi);   // out rows row0, row0+1
    EMIT(0, mlo); EMIT(1, mhi);
    S0 = LROW(row0 + 4); S1 = LROW(row0 + 5);
    pair_medians(S3, S4, S5, S0, S2, S1, mlo, mhi);   // rows +2, +3
    EMIT(2, mlo); EMIT(3, mhi);
    S2 = LROW(row0 + 6); S3 = LROW(row0 + 7);
    pair_medians(S5, S0, S1, S2, S4, S3, mlo, mhi);   // rows +4, +5
    EMIT(4, mlo); EMIT(5, mhi);
    S4 = LROW(row0 + 8); S5 = LROW(row0 + 9);
    pair_medians(S1, S2, S3, S4, S0, S5, mlo, mhi);   // rows +6, +7
    EMIT(6, mlo); EMIT(7, mhi);
#undef EMIT
#undef LROW
}

extern "C" void kernel_launch(void* const* d_in, const int* in_sizes, int n_in,
                              void* d_out, int out_size, void* d_ws, size_t ws_size,
                              hipStream_t stream) {
    const float* x = (const float*)d_in[0];
    float* out = (float*)d_out;
    const int planes = in_sizes[0] / (IMG_H * IMG_W);   // B*C = 8
    dim3 grid(IMG_W / 128, IMG_H / 32, planes);         // 2048 blocks
    dim3 block(64, 4);
    median5x5_kernel<<<grid, block, 0, stream>>>(x, out);
}